// Round 26
// baseline (152.542 us; speedup 1.0000x reference)
//
#include <hip/hip_runtime.h>

typedef unsigned short u16;
typedef unsigned char u8;
typedef float f32x4 __attribute__((ext_vector_type(4)));
typedef int i32x8 __attribute__((ext_vector_type(8)));

#define CH 512
#define HW 4096
#define TOKENS 16384
#define NGRP 32

__device__ __forceinline__ u8 f2fp8(float f) {   // OCP e4m3fn, RNE+sat
  return (u8)(__builtin_amdgcn_cvt_pk_fp8_f32(f, f, 0, false) & 0xff);
}
__device__ __forceinline__ unsigned f2fp8x4(float a, float b, float c, float d) {
  int lo = __builtin_amdgcn_cvt_pk_fp8_f32(a, b, 0, false);
  return (unsigned)__builtin_amdgcn_cvt_pk_fp8_f32(c, d, lo, true);
}
// fp4 e2m1 encode of 4*x (pre-scale x4; MFMA dequants with E8M0 scale 125 = 2^-2).
__device__ __forceinline__ unsigned nib4(float x) {
  float a = fabsf(x) * 4.0f;
  unsigned c = (unsigned)(a >= 0.25f) + (a >= 0.75f) + (a >= 1.25f) + (a >= 1.75f) +
               (a >= 2.5f) + (a >= 3.5f) + (a >= 5.0f);
  return c | ((__float_as_uint(x) >> 28) & 8u);
}
__device__ __forceinline__ u16 pk4(float a, float b, float c, float d) {
  return (u16)(nib4(a) | (nib4(b) << 4) | (nib4(c) << 8) | (nib4(d) << 12));
}

// async global->LDS, 16B per lane
#define GLOAD16(gp, lp)                                                        \
  __builtin_amdgcn_global_load_lds(                                            \
      (const __attribute__((address_space(1))) unsigned int*)(const void*)(gp),\
      (__attribute__((address_space(3))) unsigned int*)(void*)(lp), 16, 0, 0)

// fp8 frag read: 32B at swizzled offset (rows 128B, granule ^= row&7)
#define RD8(dst, buf, row) do {                                                \
    int base_ = (row) * 128, sw_ = ((row) & 7) << 4;                           \
    uint4 lo_ = *(const uint4*)(&buf[base_ + ((h * 32) ^ sw_)]);               \
    uint4 hi_ = *(const uint4*)(&buf[base_ + ((h * 32 + 16) ^ sw_)]);          \
    dst[0] = (int)lo_.x; dst[1] = (int)lo_.y; dst[2] = (int)lo_.z;             \
    dst[3] = (int)lo_.w; dst[4] = (int)hi_.x; dst[5] = (int)hi_.y;             \
    dst[6] = (int)hi_.z; dst[7] = (int)hi_.w;                                  \
  } while (0)

// fp4 frag read, 128B rows (half-K panels): granule ^= row&7, ks in {0,1}
#define RD4H(dst, buf, row, ks) do {                                           \
    uint4 t_ = *(const uint4*)(&buf[(row) * 128 +                              \
                                    (((ks) * 64 + h * 16) ^ (((row) & 7) << 4))]); \
    dst[0] = (int)t_.x; dst[1] = (int)t_.y; dst[2] = (int)t_.z;                \
    dst[3] = (int)t_.w; dst[4] = 0; dst[5] = 0; dst[6] = 0; dst[7] = 0;        \
  } while (0)

// fp4 frag read, 64B rows: 16B at swizzled offset (granule ^= row&3)
#define RD4(dst, buf, row) do {                                                \
    uint4 t_ = *(const uint4*)(&buf[(row) * 64 + ((h * 16) ^ (((row) & 3) << 4))]); \
    dst[0] = (int)t_.x; dst[1] = (int)t_.y; dst[2] = (int)t_.z;                \
    dst[3] = (int)t_.w; dst[4] = 0; dst[5] = 0; dst[6] = 0; dst[7] = 0;        \
  } while (0)

// ---------------- GroupNorm stats, stage 1: 1024 blocks of (bg, chunk) ----------------
__global__ void gn_stats_part(const float* __restrict__ x, float2* __restrict__ part) {
  int bg = blockIdx.x >> 3, ck = blockIdx.x & 7;   // bg 0..127, chunk 0..7
  int b = bg >> 5, g = bg & 31;
  const float* base = x + (size_t)b * HW * CH + g * 16;
  float s = 0.f, s2 = 0.f;
#pragma unroll
  for (int it = 0; it < 2; ++it) {
    int p = ck * 512 + it * 256 + threadIdx.x;
    const float4* row = (const float4*)(base + (size_t)p * CH);
#pragma unroll
    for (int q = 0; q < 4; ++q) {
      float4 v = row[q];
      s += v.x + v.y + v.z + v.w;
      s2 += v.x * v.x + v.y * v.y + v.z * v.z + v.w * v.w;
    }
  }
#pragma unroll
  for (int o = 32; o; o >>= 1) { s += __shfl_down(s, o); s2 += __shfl_down(s2, o); }
  __shared__ float rs[4], rs2[4];
  int wid = threadIdx.x >> 6, lane = threadIdx.x & 63;
  if (lane == 0) { rs[wid] = s; rs2[wid] = s2; }
  __syncthreads();
  if (threadIdx.x == 0)
    part[blockIdx.x] = make_float2(rs[0] + rs[1] + rs[2] + rs[3],
                                   rs2[0] + rs2[1] + rs2[2] + rs2[3]);
}

// ---------------- GroupNorm stats, stage 2: reduce 8 partials per (b,g) ----------------
__global__ void gn_finish(const float2* __restrict__ part, float2* __restrict__ stats) {
  int bg = threadIdx.x;               // 128 threads
  float S = 0.f, S2 = 0.f;
#pragma unroll
  for (int c = 0; c < 8; ++c) {
    float2 p = part[bg * 8 + c];
    S += p.x; S2 += p.y;
  }
  float mean = S * (1.f / 65536.f);
  float var = S2 * (1.f / 65536.f) - mean * mean;
  stats[bg] = make_float2(mean, rsqrtf(var + 1e-5f));
}

// ---------------- GroupNorm apply -> xn8 (fp8) ----------------
__global__ void gn_apply8(const float* __restrict__ x, const float* __restrict__ gamma,
                          const float* __restrict__ beta, const float2* __restrict__ stats,
                          u8* __restrict__ xn8) {
  size_t i = (size_t)blockIdx.x * blockDim.x + threadIdx.x;  // chunk of 8 elems
  size_t e0 = i * 8;
  int c = (int)(e0 & (CH - 1));
  size_t t = e0 >> 9;
  int b = (int)(t >> 12);
  float2 st = stats[b * NGRP + (c >> 4)];
  float4 v0 = *(const float4*)(x + t * CH + c);
  float4 v1 = *(const float4*)(x + t * CH + c + 4);
  float4 g0 = *(const float4*)(gamma + c);
  float4 g1 = *(const float4*)(gamma + c + 4);
  float4 b0 = *(const float4*)(beta + c);
  float4 b1 = *(const float4*)(beta + c + 4);
  float o[8];
  o[0] = (v0.x - st.x) * st.y * g0.x + b0.x;
  o[1] = (v0.y - st.x) * st.y * g0.y + b0.y;
  o[2] = (v0.z - st.x) * st.y * g0.z + b0.z;
  o[3] = (v0.w - st.x) * st.y * g0.w + b0.w;
  o[4] = (v1.x - st.x) * st.y * g1.x + b1.x;
  o[5] = (v1.y - st.x) * st.y * g1.y + b1.y;
  o[6] = (v1.z - st.x) * st.y * g1.z + b1.z;
  o[7] = (v1.w - st.x) * st.y * g1.w + b1.w;
  uint2 pk;
  pk.x = f2fp8x4(o[0], o[1], o[2], o[3]);
  pk.y = f2fp8x4(o[4], o[5], o[6], o[7]);
  *(uint2*)(xn8 + e0) = pk;
}

// ---------------- transpose 512x512 weights fp32 -> fp8 (T[d][c] = W[c][d]) ----------------
__global__ void transpose_w8(const float* __restrict__ W0, const float* __restrict__ W1,
                             const float* __restrict__ W2, const float* __restrict__ W3,
                             u8* __restrict__ T0, u8* __restrict__ T1,
                             u8* __restrict__ T2, u8* __restrict__ T3) {
  const float* W; u8* T;
  switch (blockIdx.z) {
    case 0: W = W0; T = T0; break;
    case 1: W = W1; T = T1; break;
    case 2: W = W2; T = T2; break;
    default: W = W3; T = T3; break;
  }
  __shared__ float tile[32][33];
  int tx = threadIdx.x, ty = threadIdx.y;
  int x0 = blockIdx.x * 32, y0 = blockIdx.y * 32;
#pragma unroll
  for (int r = 0; r < 32; r += 8) tile[ty + r][tx] = W[(size_t)(y0 + ty + r) * CH + x0 + tx];
  __syncthreads();
#pragma unroll
  for (int r = 0; r < 32; r += 8) T[(size_t)(x0 + ty + r) * CH + y0 + tx] = f2fp8(tile[tx][ty + r]);
}

// ---- QKV: MX-fp8 GEMM (single-K staging, 32 KB LDS), epilogue -> fp4 Q4,K4 + fp4 V4t ----
__global__ __launch_bounds__(256) void qkvmx(const u8* __restrict__ A,
                                             const u8* __restrict__ Bt,
                                             const float* __restrict__ bq,
                                             const float* __restrict__ bk,
                                             const float* __restrict__ bv,
                                             u8* __restrict__ Q4, u8* __restrict__ K4,
                                             u8* __restrict__ V4) {
  constexpr int BK = 128;
  const int K = CH;
  __shared__ __align__(16) u8 lA[128 * BK];
  __shared__ __align__(16) u8 lB[128 * BK];
  const int bm = blockIdx.y * 128, bn = blockIdx.x * 128;
  const int tid = threadIdx.x, lane = tid & 63, wid = tid >> 6;
  const int wm = (wid >> 1) * 64, wn = (wid & 1) * 64;
  const int r0 = lane & 15, h = lane >> 4;

  const int srow = lane >> 3;
  const int scol = ((lane & 7) * 16) ^ ((srow & 7) << 4);
  size_t aoff[4], boff[4];
#pragma unroll
  for (int s = 0; s < 4; ++s) {
    int row = wid * 32 + s * 8 + srow;
    aoff[s] = (size_t)(bm + row) * K + scol;
    boff[s] = (size_t)(bn + row) * K + scol;
  }

  f32x4 acc[4][4] = {};
  for (int kt = 0; kt < K; kt += BK) {
    __syncthreads();
#pragma unroll
    for (int s = 0; s < 4; ++s) {
      GLOAD16(A + aoff[s] + kt, &lA[(wid * 4 + s) * 1024]);
      GLOAD16(Bt + boff[s] + kt, &lB[(wid * 4 + s) * 1024]);
    }
    __syncthreads();
    i32x8 bf[4];
#pragma unroll
    for (int j = 0; j < 4; ++j) RD8(bf[j], lB, wn + j * 16 + r0);
#pragma unroll
    for (int i = 0; i < 4; ++i) {
      i32x8 af;
      RD8(af, lA, wm + i * 16 + r0);
#pragma unroll
      for (int j = 0; j < 4; ++j)
        acc[i][j] = __builtin_amdgcn_mfma_scale_f32_16x16x128_f8f6f4(
            af, bf[j], acc[i][j], 0, 0, 0, 127, 0, 127);
    }
  }

  // epilogue: D layout col(n)=lane&15, row=(lane>>4)*4+r; chunk uniform per (block, wn)
  const int chn = (bn + wn) >> 9;
  const int nb = (bn + wn) & 511;
  if (chn == 2) {                     // V: fp4, [bb][CH][HW/2], keys 4-consecutive -> u16
#pragma unroll
    for (int j = 0; j < 4; ++j) {
      int nn = nb + j * 16 + r0;
      float bvv = bv[nn];
#pragma unroll
      for (int i = 0; i < 4; ++i) {
        int m0 = bm + wm + i * 16 + h * 4;
        int bb = m0 >> 12, tl = m0 & (HW - 1);
        *(u16*)(V4 + ((size_t)bb * CH + nn) * (HW / 2) + (tl >> 1)) =
            pk4(acc[i][j][0] + bvv, acc[i][j][1] + bvv,
                acc[i][j][2] + bvv, acc[i][j][3] + bvv);
      }
    }
  } else {                            // Q/K: fp4, rows 256B, kappa-c packed u16
    u8* P4 = chn == 0 ? Q4 : K4;
    const float* bb_ = chn == 0 ? bq : bk;
    float bj[4];
#pragma unroll
    for (int j = 0; j < 4; ++j) bj[j] = bb_[nb + j * 16 + r0];
#pragma unroll
    for (int i = 0; i < 4; ++i) {
#pragma unroll
      for (int r = 0; r < 4; ++r) {
        int m0r = bm + wm + i * 16 + h * 4 + r;
        *(u16*)(P4 + (size_t)m0r * 256 + (nb >> 1) + 2 * r0) =
            pk4(acc[i][0][r] + bj[0], acc[i][1][r] + bj[1],
                acc[i][2][r] + bj[2], acc[i][3][r] + bj[3]);
      }
    }
  }
}

// ---- S-GEMM MX-fp4, SWAPPED (S^T compute), HALF-K staging: 32 KB LDS, 2 passes ----
// Each pass stages 128 B/row (K half) per panel -> 16 KB x 2, barrier, 2 ks steps.
// Occupancy cap rises 2 -> 5 blocks/CU; drains overlap across co-resident blocks.
// Swizzle algebra unchanged: granule ^= row&7 (row&7 invariant under s*32, half offset).
__global__ __launch_bounds__(256) void sgemm4(const u8* __restrict__ Kp,
                                              const u8* __restrict__ Qp,
                                              float* __restrict__ lsum,
                                              u8* __restrict__ S8,
                                              float scale,
                                              size_t sA, size_t sB, size_t sC) {
  __shared__ __align__(16) u8 lA[128 * 128];   // keys half-panel, 16 KB
  __shared__ __align__(16) u8 lB[128 * 128];   // q half-panel,    16 KB
  const int z = blockIdx.z;
  const u8* A = Kp + (size_t)z * sA;           // keys
  const u8* B = Qp + (size_t)z * sB;           // queries
  const int bm = blockIdx.y * 128;             // key block
  const int bn = blockIdx.x * 128;             // q block
  const int tid = threadIdx.x, lane = tid & 63, wid = tid >> 6;
  const int wm = (wid >> 1) * 64, wn = (wid & 1) * 64;
  const int r0 = lane & 15, h = lane >> 4;

  // staging: thread t covers 16B; dest row = (t>>3) + s*32, granule = t&7
  const int drow = tid >> 3;                   // 0..31
  const int scol = ((tid & 7) ^ (drow & 7)) * 16;
  const size_t aoff = (size_t)(bm + drow) * 256 + scol;
  const size_t boff = (size_t)(bn + drow) * 256 + scol;

  f32x4 acc[4][4] = {};
#pragma unroll
  for (int hf = 0; hf < 2; ++hf) {
    if (hf) __syncthreads();                   // prev half's reads complete
#pragma unroll
    for (int s = 0; s < 4; ++s) {
      GLOAD16(A + aoff + (size_t)s * 8192 + (size_t)hf * 128, &lA[wid * 1024 + s * 4096]);
      GLOAD16(B + boff + (size_t)s * 8192 + (size_t)hf * 128, &lB[wid * 1024 + s * 4096]);
    }
    __syncthreads();
#pragma unroll
    for (int ks = 0; ks < 2; ++ks) {
      i32x8 bf[4];
#pragma unroll
      for (int j = 0; j < 4; ++j) RD4H(bf[j], lB, wn + j * 16 + r0, ks);
#pragma unroll
      for (int i = 0; i < 4; ++i) {
        i32x8 af;
        RD4H(af, lA, wm + i * 16 + r0, ks);
#pragma unroll
        for (int j = 0; j < 4; ++j)
          acc[i][j] = __builtin_amdgcn_mfma_scale_f32_16x16x128_f8f6f4(
              af, bf[j], acc[i][j], 4, 4, 0, 125, 0, 125);
      }
    }
  }

  // epilogue: lane (i,j) holds keys {bm+wm+i*16+h*4 .. +3} at q = bn+wn+j*16+r0
  u8* C = S8 + (size_t)z * sC;
  float* lp = lsum + (size_t)(z * 64 + blockIdx.y * 2 + (wid >> 1)) * HW;
  float rs[4] = {0.f, 0.f, 0.f, 0.f};          // per-j q-rowsum partials
#pragma unroll
  for (int i = 0; i < 4; ++i) {
    int key4 = bm + wm + i * 16 + h * 4;
#pragma unroll
    for (int j = 0; j < 4; ++j) {
      int q = bn + wn + j * 16 + r0;
      float e0 = __expf(acc[i][j][0] * scale);
      float e1 = __expf(acc[i][j][1] * scale);
      float e2 = __expf(acc[i][j][2] * scale);
      float e3 = __expf(acc[i][j][3] * scale);
      rs[j] += e0 + e1 + e2 + e3;
      *(unsigned*)(C + (size_t)q * HW + key4) = f2fp8x4(e0, e1, e2, e3);
    }
  }
#pragma unroll
  for (int j = 0; j < 4; ++j) {
    float v = rs[j];
    v += __shfl_xor(v, 16);
    v += __shfl_xor(v, 32);                    // sum over h: wave's 64 keys
    if (h == 0) lp[bn + wn + j * 16 + r0] = v;
  }
}

// ---- PV SWAPPED (O^T compute), PAIRED iterations (R21 exact) ----
__global__ __launch_bounds__(256) void pv84(const u8* __restrict__ S8,
                                            const u8* __restrict__ V4,
                                            const float* __restrict__ lsum_in,
                                            u8* __restrict__ O8) {
  __shared__ __align__(16) u8 lA[2][128 * 64];   // V fp4 tiles  2x8 KB (rows=ch)
  __shared__ __align__(16) u8 lB[2][128 * 128];  // S fp8 tiles 2x16 KB (rows=q)
  __shared__ float lsum_sh[128];

  int bch, bq, z;
  if (gridDim.y == 1) {               // big path: 512 blocks, XCD-chunked swizzle
    int p = blockIdx.x;
    int xcd = p & 7, j = p >> 3;
    int xi = j & 3;                   // channel block 0..3
    int mp = xcd * 16 + (j >> 2);     // q-panel 0..127
    bch = xi * 128; bq = (mp & 31) * 128; z = mp >> 5;
  } else {
    z = blockIdx.z; bq = blockIdx.y * 128; bch = blockIdx.x * 128;
  }
  const u8* A = V4 + (size_t)z * CH * (HW / 2);
  const u8* B = S8 + (size_t)z * HW * HW;
  const float* lsum = lsum_in + (size_t)z * 64 * HW;
  u8* C = O8 + (size_t)z * HW * CH;

  const int tid = threadIdx.x, lane = tid & 63, wid = tid >> 6;
  const int wm = (wid >> 1) * 64, wn = (wid & 1) * 64;  // wm: ch, wn: q
  const int r0 = lane & 15, h = lane >> 4;

  if (tid < 128) {                    // per-q rowsums for this q block
    const float* lp = lsum + bq + tid;
    float s = 0.f;
#pragma unroll 8
    for (int p = 0; p < 64; ++p) s += lp[(size_t)p * HW];
    lsum_sh[tid] = s;
  }

  // A staging (V): rows 2048B global, tile rows 64B, granule ^= row&3
  const int srow4 = lane >> 2;
  const int scol4 = (((lane & 3) ^ (srow4 & 3)) << 4);
  size_t aoff[2];
#pragma unroll
  for (int s = 0; s < 2; ++s)
    aoff[s] = (size_t)(bch + wid * 32 + s * 16 + srow4) * (HW / 2) + scol4;
  // B staging (S): rows 4096B global, tile rows 128B, granule ^= row&7
  const int srow8 = lane >> 3;
  const int scol8 = ((lane & 7) * 16) ^ ((srow8 & 7) << 4);
  size_t boff[4];
#pragma unroll
  for (int s = 0; s < 4; ++s)
    boff[s] = (size_t)(bq + wid * 32 + s * 8 + srow8) * HW + scol8;

  f32x4 acc[4][4] = {};
  for (int kt = 0; kt < HW; kt += 256) {     // 16 paired K-steps over keys
    __syncthreads();
#pragma unroll
    for (int s = 0; s < 2; ++s) {
      GLOAD16(A + aoff[s] + (kt >> 1), &lA[0][(wid * 2 + s) * 1024]);
      GLOAD16(A + aoff[s] + (kt >> 1) + 64, &lA[1][(wid * 2 + s) * 1024]);
    }
#pragma unroll
    for (int s = 0; s < 4; ++s) {
      GLOAD16(B + boff[s] + kt, &lB[0][(wid * 4 + s) * 1024]);
      GLOAD16(B + boff[s] + kt + 128, &lB[1][(wid * 4 + s) * 1024]);
    }
    __syncthreads();
#pragma unroll
    for (int half = 0; half < 2; ++half) {
      i32x8 bf[4];
#pragma unroll
      for (int j = 0; j < 4; ++j) RD8(bf[j], lB[half], wn + j * 16 + r0);
#pragma unroll
      for (int i = 0; i < 4; ++i) {
        i32x8 af;
        RD4(af, lA[half], wm + i * 16 + r0);
#pragma unroll
        for (int j = 0; j < 4; ++j)
          acc[i][j] = __builtin_amdgcn_mfma_scale_f32_16x16x128_f8f6f4(
              af, bf[j], acc[i][j], 4, 0, 0, 125, 0, 127);
      }
    }
  }

  // epilogue: lane (i,j) holds channels {bch+wm+i*16+h*4 ..+3} at q = bq+wn+j*16+r0
#pragma unroll
  for (int i = 0; i < 4; ++i) {
    int ch4 = bch + wm + i * 16 + h * 4;
#pragma unroll
    for (int j = 0; j < 4; ++j) {
      int ql = wn + j * 16 + r0;
      float inv = 1.0f / lsum_sh[ql];
      *(unsigned*)(C + (size_t)(bq + ql) * CH + ch4) =
          f2fp8x4(acc[i][j][0] * inv, acc[i][j][1] * inv,
                  acc[i][j][2] * inv, acc[i][j][3] * inv);
    }
  }
}

// ---- proj: MX-fp8 GEMM (single-K staging, 32 KB LDS), f32 out + bias + residual ----
__global__ __launch_bounds__(256) void projmx(const u8* __restrict__ A,
                                              const u8* __restrict__ Bt,
                                              const float* __restrict__ bias,
                                              const float* __restrict__ residual,
                                              float* __restrict__ Cout) {
  constexpr int BK = 128;
  const int K = CH, N = CH;
  __shared__ __align__(16) u8 lA[128 * BK];
  __shared__ __align__(16) u8 lB[128 * BK];
  const int bm = blockIdx.y * 128, bn = blockIdx.x * 128;
  const int tid = threadIdx.x, lane = tid & 63, wid = tid >> 6;
  const int wm = (wid >> 1) * 64, wn = (wid & 1) * 64;
  const int r0 = lane & 15, h = lane >> 4;

  const int srow = lane >> 3;
  const int scol = ((lane & 7) * 16) ^ ((srow & 7) << 4);
  size_t aoff[4], boff[4];
#pragma unroll
  for (int s = 0; s < 4; ++s) {
    int row = wid * 32 + s * 8 + srow;
    aoff[s] = (size_t)(bm + row) * K + scol;
    boff[s] = (size_t)(bn + row) * K + scol;
  }

  f32x4 acc[4][4] = {};
  for (int kt = 0; kt < K; kt += BK) {
    __syncthreads();
#pragma unroll
    for (int s = 0; s < 4; ++s) {
      GLOAD16(A + aoff[s] + kt, &lA[(wid * 4 + s) * 1024]);
      GLOAD16(Bt + boff[s] + kt, &lB[(wid * 4 + s) * 1024]);
    }
    __syncthreads();
    i32x8 bf[4];
#pragma unroll
    for (int j = 0; j < 4; ++j) RD8(bf[j], lB, wn + j * 16 + r0);
#pragma unroll
    for (int i = 0; i < 4; ++i) {
      i32x8 af;
      RD8(af, lA, wm + i * 16 + r0);
#pragma unroll
      for (int j = 0; j < 4; ++j)
        acc[i][j] = __builtin_amdgcn_mfma_scale_f32_16x16x128_f8f6f4(
            af, bf[j], acc[i][j], 0, 0, 0, 127, 0, 127);
    }
  }

#pragma unroll
  for (int j = 0; j < 4; ++j) {
    int n = bn + wn + j * 16 + r0;
    float bvv = bias[n];
#pragma unroll
    for (int i = 0; i < 4; ++i) {
      int m0 = bm + wm + i * 16 + h * 4;
#pragma unroll
      for (int r = 0; r < 4; ++r) {
        size_t idx = (size_t)(m0 + r) * N + n;
        Cout[idx] = acc[i][j][r] + bvv + residual[idx];
      }
    }
  }
}

extern "C" void kernel_launch(void* const* d_in, const int* in_sizes, int n_in,
                              void* d_out, int out_size, void* d_ws, size_t ws_size,
                              hipStream_t stream) {
  (void)in_sizes; (void)n_in; (void)out_size;
  const float* x     = (const float*)d_in[0];
  const float* gamma = (const float*)d_in[1];
  const float* beta  = (const float*)d_in[2];
  const float* Wq    = (const float*)d_in[3];
  const float* bq    = (const float*)d_in[4];
  const float* Wk    = (const float*)d_in[5];
  const float* bk    = (const float*)d_in[6];
  const float* Wv    = (const float*)d_in[7];
  const float* bv    = (const float*)d_in[8];
  const float* Wp    = (const float*)d_in[9];
  const float* bp    = (const float*)d_in[10];
  float* out = (float*)d_out;

  char* ws = (char*)d_ws;
  size_t off = 0;
  auto alloc = [&](size_t bytes) -> void* {
    void* p = ws + off;
    off += (bytes + 255) & ~(size_t)255;
    return p;
  };
  const size_t X8  = (size_t)TOKENS * CH;         // 8 MB fp8
  const size_t X4  = (size_t)TOKENS * CH / 2;     // 4 MB fp4
  const size_t W8  = (size_t)CH * CH;             // 0.25 MB fp8
  const size_t S8B = (size_t)HW * HW;             // 16.8 MB fp8 per batch
  const size_t LS  = (size_t)4 * 64 * HW * sizeof(float);  // 4 MB partial rowsums
  const size_t need_all = 2 * 1024 * 1024 + LS + 2 * X8 + 3 * X4 + 4 * W8 + 4 * S8B;
  const bool big = ws_size >= need_all;           // deterministic across calls

  float2* stats    = (float2*)alloc(128 * sizeof(float2));
  float2* gpart    = (float2*)alloc(1024 * sizeof(float2));
  float* lsum_part = (float*)alloc(LS);           // [z][64][HW]
  u8* xn8   = (u8*)alloc(X8);    // fp8 normalized input
  u8* O8    = (u8*)alloc(X8);    // fp8 attention out
  u8* Q4    = (u8*)alloc(X4);    // fp4 (x4 pre-scaled), kappa-c channel order
  u8* K4    = (u8*)alloc(X4);
  u8* V4    = (u8*)alloc(X4);    // fp4 [B][CH][HW/2]
  u8* Wqkv8 = (u8*)alloc(3 * W8);
  u8* Wp8   = (u8*)alloc(W8);
  u8* S8    = (u8*)alloc(big ? 4 * S8B : S8B);

  gn_stats_part<<<1024, 256, 0, stream>>>(x, gpart);
  gn_finish<<<1, 128, 0, stream>>>(gpart, stats);
  gn_apply8<<<TOKENS * CH / 8 / 256, 256, 0, stream>>>(x, gamma, beta, stats, xn8);
  transpose_w8<<<dim3(16, 16, 4), dim3(32, 8), 0, stream>>>(
      Wq, Wk, Wv, Wp, Wqkv8, Wqkv8 + (size_t)CH * CH, Wqkv8 + 2 * (size_t)CH * CH, Wp8);

  qkvmx<<<dim3(1536 / 128, TOKENS / 128), 256, 0, stream>>>(
      xn8, Wqkv8, bq, bk, bv, Q4, K4, V4);

  const float scl = 0.044194173824159216f;  // 1/sqrt(512)
  const size_t sQ = (size_t)HW * 256;       // fp4 row = 256 B
  if (big) {
    sgemm4<<<dim3(32, 32, 4), 256, 0, stream>>>(
        K4, Q4, lsum_part, S8, scl, sQ, sQ, (size_t)HW * HW);
    pv84<<<dim3(512, 1, 1), 256, 0, stream>>>(S8, V4, lsum_part, O8);
  } else {
    for (int b = 0; b < 4; ++b) {
      sgemm4<<<dim3(32, 32, 1), 256, 0, stream>>>(
          K4 + (size_t)b * sQ, Q4 + (size_t)b * sQ,
          lsum_part + (size_t)b * 64 * HW, S8, scl, 0, 0, 0);
      pv84<<<dim3(4, 32, 1), 256, 0, stream>>>(
          S8, V4 + (size_t)b * CH * (HW / 2),
          lsum_part + (size_t)b * 64 * HW, O8 + (size_t)b * HW * CH);
    }
  }

  projmx<<<dim3(4, TOKENS / 128), 256, 0, stream>>>(O8, Wp8, bp, x, out);
}

// Round 27
// 150.706 us; speedup vs baseline: 1.0122x; 1.0122x over previous
//
#include <hip/hip_runtime.h>

typedef unsigned short u16;
typedef unsigned char u8;
typedef float f32x4 __attribute__((ext_vector_type(4)));
typedef int i32x8 __attribute__((ext_vector_type(8)));

#define CH 512
#define HW 4096
#define TOKENS 16384
#define NGRP 32

__device__ __forceinline__ u8 f2fp8(float f) {   // OCP e4m3fn, RNE+sat
  return (u8)(__builtin_amdgcn_cvt_pk_fp8_f32(f, f, 0, false) & 0xff);
}
__device__ __forceinline__ unsigned f2fp8x4(float a, float b, float c, float d) {
  int lo = __builtin_amdgcn_cvt_pk_fp8_f32(a, b, 0, false);
  return (unsigned)__builtin_amdgcn_cvt_pk_fp8_f32(c, d, lo, true);
}
// fp4 e2m1 encode of 4*x (pre-scale x4; MFMA dequants with E8M0 scale 125 = 2^-2).
__device__ __forceinline__ unsigned nib4(float x) {
  float a = fabsf(x) * 4.0f;
  unsigned c = (unsigned)(a >= 0.25f) + (a >= 0.75f) + (a >= 1.25f) + (a >= 1.75f) +
               (a >= 2.5f) + (a >= 3.5f) + (a >= 5.0f);
  return c | ((__float_as_uint(x) >> 28) & 8u);
}
__device__ __forceinline__ u16 pk4(float a, float b, float c, float d) {
  return (u16)(nib4(a) | (nib4(b) << 4) | (nib4(c) << 8) | (nib4(d) << 12));
}

// async global->LDS, 16B per lane
#define GLOAD16(gp, lp)                                                        \
  __builtin_amdgcn_global_load_lds(                                            \
      (const __attribute__((address_space(1))) unsigned int*)(const void*)(gp),\
      (__attribute__((address_space(3))) unsigned int*)(void*)(lp), 16, 0, 0)

// fp8 frag read: 32B at swizzled offset (rows 128B, granule ^= row&7)
#define RD8(dst, buf, row) do {                                                \
    int base_ = (row) * 128, sw_ = ((row) & 7) << 4;                           \
    uint4 lo_ = *(const uint4*)(&buf[base_ + ((h * 32) ^ sw_)]);               \
    uint4 hi_ = *(const uint4*)(&buf[base_ + ((h * 32 + 16) ^ sw_)]);          \
    dst[0] = (int)lo_.x; dst[1] = (int)lo_.y; dst[2] = (int)lo_.z;             \
    dst[3] = (int)lo_.w; dst[4] = (int)hi_.x; dst[5] = (int)hi_.y;             \
    dst[6] = (int)hi_.z; dst[7] = (int)hi_.w;                                  \
  } while (0)

// fp4 frag read, 256B rows: 16B at swizzled offset (granule ^= row&7)
#define RD4W(dst, buf, row, ks) do {                                           \
    uint4 t_ = *(const uint4*)(&buf[(row) * 256 +                              \
                                    (((ks) * 64 + h * 16) ^ (((row) & 7) << 4))]); \
    dst[0] = (int)t_.x; dst[1] = (int)t_.y; dst[2] = (int)t_.z;                \
    dst[3] = (int)t_.w; dst[4] = 0; dst[5] = 0; dst[6] = 0; dst[7] = 0;        \
  } while (0)

// fp4 frag read, 64B rows: 16B at swizzled offset (granule ^= row&3)
#define RD4(dst, buf, row) do {                                                \
    uint4 t_ = *(const uint4*)(&buf[(row) * 64 + ((h * 16) ^ (((row) & 3) << 4))]); \
    dst[0] = (int)t_.x; dst[1] = (int)t_.y; dst[2] = (int)t_.z;                \
    dst[3] = (int)t_.w; dst[4] = 0; dst[5] = 0; dst[6] = 0; dst[7] = 0;        \
  } while (0)

// ---------------- GroupNorm stats, stage 1: 1024 blocks of (bg, chunk) ----------------
__global__ void gn_stats_part(const float* __restrict__ x, float2* __restrict__ part) {
  int bg = blockIdx.x >> 3, ck = blockIdx.x & 7;   // bg 0..127, chunk 0..7
  int b = bg >> 5, g = bg & 31;
  const float* base = x + (size_t)b * HW * CH + g * 16;
  float s = 0.f, s2 = 0.f;
#pragma unroll
  for (int it = 0; it < 2; ++it) {
    int p = ck * 512 + it * 256 + threadIdx.x;
    const float4* row = (const float4*)(base + (size_t)p * CH);
#pragma unroll
    for (int q = 0; q < 4; ++q) {
      float4 v = row[q];
      s += v.x + v.y + v.z + v.w;
      s2 += v.x * v.x + v.y * v.y + v.z * v.z + v.w * v.w;
    }
  }
#pragma unroll
  for (int o = 32; o; o >>= 1) { s += __shfl_down(s, o); s2 += __shfl_down(s2, o); }
  __shared__ float rs[4], rs2[4];
  int wid = threadIdx.x >> 6, lane = threadIdx.x & 63;
  if (lane == 0) { rs[wid] = s; rs2[wid] = s2; }
  __syncthreads();
  if (threadIdx.x == 0)
    part[blockIdx.x] = make_float2(rs[0] + rs[1] + rs[2] + rs[3],
                                   rs2[0] + rs2[1] + rs2[2] + rs2[3]);
}

// ---------------- GroupNorm stats, stage 2: reduce 8 partials per (b,g) ----------------
__global__ void gn_finish(const float2* __restrict__ part, float2* __restrict__ stats) {
  int bg = threadIdx.x;               // 128 threads
  float S = 0.f, S2 = 0.f;
#pragma unroll
  for (int c = 0; c < 8; ++c) {
    float2 p = part[bg * 8 + c];
    S += p.x; S2 += p.y;
  }
  float mean = S * (1.f / 65536.f);
  float var = S2 * (1.f / 65536.f) - mean * mean;
  stats[bg] = make_float2(mean, rsqrtf(var + 1e-5f));
}

// ---------------- GroupNorm apply -> xn8 (fp8) ----------------
__global__ void gn_apply8(const float* __restrict__ x, const float* __restrict__ gamma,
                          const float* __restrict__ beta, const float2* __restrict__ stats,
                          u8* __restrict__ xn8) {
  size_t i = (size_t)blockIdx.x * blockDim.x + threadIdx.x;  // chunk of 8 elems
  size_t e0 = i * 8;
  int c = (int)(e0 & (CH - 1));
  size_t t = e0 >> 9;
  int b = (int)(t >> 12);
  float2 st = stats[b * NGRP + (c >> 4)];
  float4 v0 = *(const float4*)(x + t * CH + c);
  float4 v1 = *(const float4*)(x + t * CH + c + 4);
  float4 g0 = *(const float4*)(gamma + c);
  float4 g1 = *(const float4*)(gamma + c + 4);
  float4 b0 = *(const float4*)(beta + c);
  float4 b1 = *(const float4*)(beta + c + 4);
  float o[8];
  o[0] = (v0.x - st.x) * st.y * g0.x + b0.x;
  o[1] = (v0.y - st.x) * st.y * g0.y + b0.y;
  o[2] = (v0.z - st.x) * st.y * g0.z + b0.z;
  o[3] = (v0.w - st.x) * st.y * g0.w + b0.w;
  o[4] = (v1.x - st.x) * st.y * g1.x + b1.x;
  o[5] = (v1.y - st.x) * st.y * g1.y + b1.y;
  o[6] = (v1.z - st.x) * st.y * g1.z + b1.z;
  o[7] = (v1.w - st.x) * st.y * g1.w + b1.w;
  uint2 pk;
  pk.x = f2fp8x4(o[0], o[1], o[2], o[3]);
  pk.y = f2fp8x4(o[4], o[5], o[6], o[7]);
  *(uint2*)(xn8 + e0) = pk;
}

// ---------------- transpose 512x512 weights fp32 -> fp8 (T[d][c] = W[c][d]) ----------------
__global__ void transpose_w8(const float* __restrict__ W0, const float* __restrict__ W1,
                             const float* __restrict__ W2, const float* __restrict__ W3,
                             u8* __restrict__ T0, u8* __restrict__ T1,
                             u8* __restrict__ T2, u8* __restrict__ T3) {
  const float* W; u8* T;
  switch (blockIdx.z) {
    case 0: W = W0; T = T0; break;
    case 1: W = W1; T = T1; break;
    case 2: W = W2; T = T2; break;
    default: W = W3; T = T3; break;
  }
  __shared__ float tile[32][33];
  int tx = threadIdx.x, ty = threadIdx.y;
  int x0 = blockIdx.x * 32, y0 = blockIdx.y * 32;
#pragma unroll
  for (int r = 0; r < 32; r += 8) tile[ty + r][tx] = W[(size_t)(y0 + ty + r) * CH + x0 + tx];
  __syncthreads();
#pragma unroll
  for (int r = 0; r < 32; r += 8) T[(size_t)(x0 + ty + r) * CH + y0 + tx] = f2fp8(tile[tx][ty + r]);
}

// ---- QKV: MX-fp8 GEMM (single-K staging, 32 KB LDS), epilogue -> fp4 Q4,K4 + fp4 V4t ----
__global__ __launch_bounds__(256) void qkvmx(const u8* __restrict__ A,
                                             const u8* __restrict__ Bt,
                                             const float* __restrict__ bq,
                                             const float* __restrict__ bk,
                                             const float* __restrict__ bv,
                                             u8* __restrict__ Q4, u8* __restrict__ K4,
                                             u8* __restrict__ V4) {
  constexpr int BK = 128;
  const int K = CH;
  __shared__ __align__(16) u8 lA[128 * BK];
  __shared__ __align__(16) u8 lB[128 * BK];
  const int bm = blockIdx.y * 128, bn = blockIdx.x * 128;
  const int tid = threadIdx.x, lane = tid & 63, wid = tid >> 6;
  const int wm = (wid >> 1) * 64, wn = (wid & 1) * 64;
  const int r0 = lane & 15, h = lane >> 4;

  const int srow = lane >> 3;
  const int scol = ((lane & 7) * 16) ^ ((srow & 7) << 4);
  size_t aoff[4], boff[4];
#pragma unroll
  for (int s = 0; s < 4; ++s) {
    int row = wid * 32 + s * 8 + srow;
    aoff[s] = (size_t)(bm + row) * K + scol;
    boff[s] = (size_t)(bn + row) * K + scol;
  }

  f32x4 acc[4][4] = {};
  for (int kt = 0; kt < K; kt += BK) {
    __syncthreads();
#pragma unroll
    for (int s = 0; s < 4; ++s) {
      GLOAD16(A + aoff[s] + kt, &lA[(wid * 4 + s) * 1024]);
      GLOAD16(Bt + boff[s] + kt, &lB[(wid * 4 + s) * 1024]);
    }
    __syncthreads();
    i32x8 bf[4];
#pragma unroll
    for (int j = 0; j < 4; ++j) RD8(bf[j], lB, wn + j * 16 + r0);
#pragma unroll
    for (int i = 0; i < 4; ++i) {
      i32x8 af;
      RD8(af, lA, wm + i * 16 + r0);
#pragma unroll
      for (int j = 0; j < 4; ++j)
        acc[i][j] = __builtin_amdgcn_mfma_scale_f32_16x16x128_f8f6f4(
            af, bf[j], acc[i][j], 0, 0, 0, 127, 0, 127);
    }
  }

  // epilogue: D layout col(n)=lane&15, row=(lane>>4)*4+r; chunk uniform per (block, wn)
  const int chn = (bn + wn) >> 9;
  const int nb = (bn + wn) & 511;
  if (chn == 2) {                     // V: fp4, [bb][CH][HW/2], keys 4-consecutive -> u16
#pragma unroll
    for (int j = 0; j < 4; ++j) {
      int nn = nb + j * 16 + r0;
      float bvv = bv[nn];
#pragma unroll
      for (int i = 0; i < 4; ++i) {
        int m0 = bm + wm + i * 16 + h * 4;
        int bb = m0 >> 12, tl = m0 & (HW - 1);
        *(u16*)(V4 + ((size_t)bb * CH + nn) * (HW / 2) + (tl >> 1)) =
            pk4(acc[i][j][0] + bvv, acc[i][j][1] + bvv,
                acc[i][j][2] + bvv, acc[i][j][3] + bvv);
      }
    }
  } else {                            // Q/K: fp4, rows 256B, kappa-c packed u16
    u8* P4 = chn == 0 ? Q4 : K4;
    const float* bb_ = chn == 0 ? bq : bk;
    float bj[4];
#pragma unroll
    for (int j = 0; j < 4; ++j) bj[j] = bb_[nb + j * 16 + r0];
#pragma unroll
    for (int i = 0; i < 4; ++i) {
#pragma unroll
      for (int r = 0; r < 4; ++r) {
        int m0r = bm + wm + i * 16 + h * 4 + r;
        *(u16*)(P4 + (size_t)m0r * 256 + (nb >> 1) + 2 * r0) =
            pk4(acc[i][0][r] + bj[0], acc[i][1][r] + bj[1],
                acc[i][2][r] + bj[2], acc[i][3][r] + bj[3]);
      }
    }
  }
}

// ---- S-GEMM MX-fp4, SWAPPED (S^T compute), full-K staging (R18/R23/R25 exact) ----
__global__ __launch_bounds__(256) void sgemm4(const u8* __restrict__ Kp,
                                              const u8* __restrict__ Qp,
                                              float* __restrict__ lsum,
                                              u8* __restrict__ S8,
                                              float scale,
                                              size_t sA, size_t sB, size_t sC) {
  __shared__ __align__(16) u8 lA[128 * 256];   // keys panel, 32 KB
  __shared__ __align__(16) u8 lB[128 * 256];   // q panel,    32 KB
  const int z = blockIdx.z;
  const u8* A = Kp + (size_t)z * sA;           // keys
  const u8* B = Qp + (size_t)z * sB;           // queries
  const int bm = blockIdx.y * 128;             // key block
  const int bn = blockIdx.x * 128;             // q block
  const int tid = threadIdx.x, lane = tid & 63, wid = tid >> 6;
  const int wm = (wid >> 1) * 64, wn = (wid & 1) * 64;
  const int r0 = lane & 15, h = lane >> 4;

  const int drow = tid >> 4;
  const int scol = ((tid & 15) ^ (drow & 7)) * 16;
  const size_t aoff = (size_t)(bm + drow) * 256 + scol;
  const size_t boff = (size_t)(bn + drow) * 256 + scol;
#pragma unroll
  for (int s = 0; s < 8; ++s) {
    GLOAD16(A + aoff + (size_t)s * 4096, &lA[wid * 1024 + s * 4096]);
    GLOAD16(B + boff + (size_t)s * 4096, &lB[wid * 1024 + s * 4096]);
  }
  __syncthreads();

  f32x4 acc[4][4] = {};
#pragma unroll
  for (int ks = 0; ks < 4; ++ks) {
    i32x8 bf[4];
#pragma unroll
    for (int j = 0; j < 4; ++j) RD4W(bf[j], lB, wn + j * 16 + r0, ks);
#pragma unroll
    for (int i = 0; i < 4; ++i) {
      i32x8 af;
      RD4W(af, lA, wm + i * 16 + r0, ks);
#pragma unroll
      for (int j = 0; j < 4; ++j)
        acc[i][j] = __builtin_amdgcn_mfma_scale_f32_16x16x128_f8f6f4(
            af, bf[j], acc[i][j], 4, 4, 0, 125, 0, 125);
    }
  }

  // epilogue: lane (i,j) holds keys {bm+wm+i*16+h*4 .. +3} at q = bn+wn+j*16+r0
  u8* C = S8 + (size_t)z * sC;
  float* lp = lsum + (size_t)(z * 64 + blockIdx.y * 2 + (wid >> 1)) * HW;
  float rs[4] = {0.f, 0.f, 0.f, 0.f};          // per-j q-rowsum partials
#pragma unroll
  for (int i = 0; i < 4; ++i) {
    int key4 = bm + wm + i * 16 + h * 4;
#pragma unroll
    for (int j = 0; j < 4; ++j) {
      int q = bn + wn + j * 16 + r0;
      float e0 = __expf(acc[i][j][0] * scale);
      float e1 = __expf(acc[i][j][1] * scale);
      float e2 = __expf(acc[i][j][2] * scale);
      float e3 = __expf(acc[i][j][3] * scale);
      rs[j] += e0 + e1 + e2 + e3;
      *(unsigned*)(C + (size_t)q * HW + key4) = f2fp8x4(e0, e1, e2, e3);
    }
  }
#pragma unroll
  for (int j = 0; j < 4; ++j) {
    float v = rs[j];
    v += __shfl_xor(v, 16);
    v += __shfl_xor(v, 32);                    // sum over h: wave's 64 keys
    if (h == 0) lp[bn + wn + j * 16 + r0] = v;
  }
}

// ---- PV SWAPPED (O^T compute), PAIRED iterations (R21 exact) ----
__global__ __launch_bounds__(256) void pv84(const u8* __restrict__ S8,
                                            const u8* __restrict__ V4,
                                            const float* __restrict__ lsum_in,
                                            u8* __restrict__ O8) {
  __shared__ __align__(16) u8 lA[2][128 * 64];   // V fp4 tiles  2x8 KB (rows=ch)
  __shared__ __align__(16) u8 lB[2][128 * 128];  // S fp8 tiles 2x16 KB (rows=q)
  __shared__ float lsum_sh[128];

  int bch, bq, z;
  if (gridDim.y == 1) {               // big path: 512 blocks, XCD-chunked swizzle
    int p = blockIdx.x;
    int xcd = p & 7, j = p >> 3;
    int xi = j & 3;                   // channel block 0..3
    int mp = xcd * 16 + (j >> 2);     // q-panel 0..127
    bch = xi * 128; bq = (mp & 31) * 128; z = mp >> 5;
  } else {
    z = blockIdx.z; bq = blockIdx.y * 128; bch = blockIdx.x * 128;
  }
  const u8* A = V4 + (size_t)z * CH * (HW / 2);
  const u8* B = S8 + (size_t)z * HW * HW;
  const float* lsum = lsum_in + (size_t)z * 64 * HW;
  u8* C = O8 + (size_t)z * HW * CH;

  const int tid = threadIdx.x, lane = tid & 63, wid = tid >> 6;
  const int wm = (wid >> 1) * 64, wn = (wid & 1) * 64;  // wm: ch, wn: q
  const int r0 = lane & 15, h = lane >> 4;

  if (tid < 128) {                    // per-q rowsums for this q block
    const float* lp = lsum + bq + tid;
    float s = 0.f;
#pragma unroll 8
    for (int p = 0; p < 64; ++p) s += lp[(size_t)p * HW];
    lsum_sh[tid] = s;
  }

  // A staging (V): rows 2048B global, tile rows 64B, granule ^= row&3
  const int srow4 = lane >> 2;
  const int scol4 = (((lane & 3) ^ (srow4 & 3)) << 4);
  size_t aoff[2];
#pragma unroll
  for (int s = 0; s < 2; ++s)
    aoff[s] = (size_t)(bch + wid * 32 + s * 16 + srow4) * (HW / 2) + scol4;
  // B staging (S): rows 4096B global, tile rows 128B, granule ^= row&7
  const int srow8 = lane >> 3;
  const int scol8 = ((lane & 7) * 16) ^ ((srow8 & 7) << 4);
  size_t boff[4];
#pragma unroll
  for (int s = 0; s < 4; ++s)
    boff[s] = (size_t)(bq + wid * 32 + s * 8 + srow8) * HW + scol8;

  f32x4 acc[4][4] = {};
  for (int kt = 0; kt < HW; kt += 256) {     // 16 paired K-steps over keys
    __syncthreads();
#pragma unroll
    for (int s = 0; s < 2; ++s) {
      GLOAD16(A + aoff[s] + (kt >> 1), &lA[0][(wid * 2 + s) * 1024]);
      GLOAD16(A + aoff[s] + (kt >> 1) + 64, &lA[1][(wid * 2 + s) * 1024]);
    }
#pragma unroll
    for (int s = 0; s < 4; ++s) {
      GLOAD16(B + boff[s] + kt, &lB[0][(wid * 4 + s) * 1024]);
      GLOAD16(B + boff[s] + kt + 128, &lB[1][(wid * 4 + s) * 1024]);
    }
    __syncthreads();
#pragma unroll
    for (int half = 0; half < 2; ++half) {
      i32x8 bf[4];
#pragma unroll
      for (int j = 0; j < 4; ++j) RD8(bf[j], lB[half], wn + j * 16 + r0);
#pragma unroll
      for (int i = 0; i < 4; ++i) {
        i32x8 af;
        RD4(af, lA[half], wm + i * 16 + r0);
#pragma unroll
        for (int j = 0; j < 4; ++j)
          acc[i][j] = __builtin_amdgcn_mfma_scale_f32_16x16x128_f8f6f4(
              af, bf[j], acc[i][j], 4, 0, 0, 125, 0, 127);
      }
    }
  }

  // epilogue: lane (i,j) holds channels {bch+wm+i*16+h*4 ..+3} at q = bq+wn+j*16+r0
#pragma unroll
  for (int i = 0; i < 4; ++i) {
    int ch4 = bch + wm + i * 16 + h * 4;
#pragma unroll
    for (int j = 0; j < 4; ++j) {
      int ql = wn + j * 16 + r0;
      float inv = 1.0f / lsum_sh[ql];
      *(unsigned*)(C + (size_t)(bq + ql) * CH + ch4) =
          f2fp8x4(acc[i][j][0] * inv, acc[i][j][1] * inv,
                  acc[i][j][2] * inv, acc[i][j][3] * inv);
    }
  }
}

// ---- proj: MX-fp8 GEMM (single-K staging, 32 KB LDS), f32 out + bias + residual ----
__global__ __launch_bounds__(256) void projmx(const u8* __restrict__ A,
                                              const u8* __restrict__ Bt,
                                              const float* __restrict__ bias,
                                              const float* __restrict__ residual,
                                              float* __restrict__ Cout) {
  constexpr int BK = 128;
  const int K = CH, N = CH;
  __shared__ __align__(16) u8 lA[128 * BK];
  __shared__ __align__(16) u8 lB[128 * BK];
  const int bm = blockIdx.y * 128, bn = blockIdx.x * 128;
  const int tid = threadIdx.x, lane = tid & 63, wid = tid >> 6;
  const int wm = (wid >> 1) * 64, wn = (wid & 1) * 64;
  const int r0 = lane & 15, h = lane >> 4;

  const int srow = lane >> 3;
  const int scol = ((lane & 7) * 16) ^ ((srow & 7) << 4);
  size_t aoff[4], boff[4];
#pragma unroll
  for (int s = 0; s < 4; ++s) {
    int row = wid * 32 + s * 8 + srow;
    aoff[s] = (size_t)(bm + row) * K + scol;
    boff[s] = (size_t)(bn + row) * K + scol;
  }

  f32x4 acc[4][4] = {};
  for (int kt = 0; kt < K; kt += BK) {
    __syncthreads();
#pragma unroll
    for (int s = 0; s < 4; ++s) {
      GLOAD16(A + aoff[s] + kt, &lA[(wid * 4 + s) * 1024]);
      GLOAD16(Bt + boff[s] + kt, &lB[(wid * 4 + s) * 1024]);
    }
    __syncthreads();
    i32x8 bf[4];
#pragma unroll
    for (int j = 0; j < 4; ++j) RD8(bf[j], lB, wn + j * 16 + r0);
#pragma unroll
    for (int i = 0; i < 4; ++i) {
      i32x8 af;
      RD8(af, lA, wm + i * 16 + r0);
#pragma unroll
      for (int j = 0; j < 4; ++j)
        acc[i][j] = __builtin_amdgcn_mfma_scale_f32_16x16x128_f8f6f4(
            af, bf[j], acc[i][j], 0, 0, 0, 127, 0, 127);
    }
  }

#pragma unroll
  for (int j = 0; j < 4; ++j) {
    int n = bn + wn + j * 16 + r0;
    float bvv = bias[n];
#pragma unroll
    for (int i = 0; i < 4; ++i) {
      int m0 = bm + wm + i * 16 + h * 4;
#pragma unroll
      for (int r = 0; r < 4; ++r) {
        size_t idx = (size_t)(m0 + r) * N + n;
        Cout[idx] = acc[i][j][r] + bvv + residual[idx];
      }
    }
  }
}

extern "C" void kernel_launch(void* const* d_in, const int* in_sizes, int n_in,
                              void* d_out, int out_size, void* d_ws, size_t ws_size,
                              hipStream_t stream) {
  (void)in_sizes; (void)n_in; (void)out_size;
  const float* x     = (const float*)d_in[0];
  const float* gamma = (const float*)d_in[1];
  const float* beta  = (const float*)d_in[2];
  const float* Wq    = (const float*)d_in[3];
  const float* bq    = (const float*)d_in[4];
  const float* Wk    = (const float*)d_in[5];
  const float* bk    = (const float*)d_in[6];
  const float* Wv    = (const float*)d_in[7];
  const float* bv    = (const float*)d_in[8];
  const float* Wp    = (const float*)d_in[9];
  const float* bp    = (const float*)d_in[10];
  float* out = (float*)d_out;

  char* ws = (char*)d_ws;
  size_t off = 0;
  auto alloc = [&](size_t bytes) -> void* {
    void* p = ws + off;
    off += (bytes + 255) & ~(size_t)255;
    return p;
  };
  const size_t X8  = (size_t)TOKENS * CH;         // 8 MB fp8
  const size_t X4  = (size_t)TOKENS * CH / 2;     // 4 MB fp4
  const size_t W8  = (size_t)CH * CH;             // 0.25 MB fp8
  const size_t S8B = (size_t)HW * HW;             // 16.8 MB fp8 per batch
  const size_t LS  = (size_t)4 * 64 * HW * sizeof(float);  // 4 MB partial rowsums
  const size_t need_all = 2 * 1024 * 1024 + LS + 2 * X8 + 3 * X4 + 4 * W8 + 4 * S8B;
  const bool big = ws_size >= need_all;           // deterministic across calls

  float2* stats    = (float2*)alloc(128 * sizeof(float2));
  float2* gpart    = (float2*)alloc(1024 * sizeof(float2));
  float* lsum_part = (float*)alloc(LS);           // [z][64][HW]
  u8* xn8   = (u8*)alloc(X8);    // fp8 normalized input
  u8* O8    = (u8*)alloc(X8);    // fp8 attention out
  u8* Q4    = (u8*)alloc(X4);    // fp4 (x4 pre-scaled), kappa-c channel order
  u8* K4    = (u8*)alloc(X4);
  u8* V4    = (u8*)alloc(X4);    // fp4 [B][CH][HW/2]
  u8* Wqkv8 = (u8*)alloc(3 * W8);
  u8* Wp8   = (u8*)alloc(W8);
  u8* S8    = (u8*)alloc(big ? 4 * S8B : S8B);

  gn_stats_part<<<1024, 256, 0, stream>>>(x, gpart);
  gn_finish<<<1, 128, 0, stream>>>(gpart, stats);
  gn_apply8<<<TOKENS * CH / 8 / 256, 256, 0, stream>>>(x, gamma, beta, stats, xn8);
  transpose_w8<<<dim3(16, 16, 4), dim3(32, 8), 0, stream>>>(
      Wq, Wk, Wv, Wp, Wqkv8, Wqkv8 + (size_t)CH * CH, Wqkv8 + 2 * (size_t)CH * CH, Wp8);

  qkvmx<<<dim3(1536 / 128, TOKENS / 128), 256, 0, stream>>>(
      xn8, Wqkv8, bq, bk, bv, Q4, K4, V4);

  const float scl = 0.044194173824159216f;  // 1/sqrt(512)
  const size_t sQ = (size_t)HW * 256;       // fp4 row = 256 B
  if (big) {
    sgemm4<<<dim3(32, 32, 4), 256, 0, stream>>>(
        K4, Q4, lsum_part, S8, scl, sQ, sQ, (size_t)HW * HW);
    pv84<<<dim3(512, 1, 1), 256, 0, stream>>>(S8, V4, lsum_part, O8);
  } else {
    for (int b = 0; b < 4; ++b) {
      sgemm4<<<dim3(32, 32, 1), 256, 0, stream>>>(
          K4 + (size_t)b * sQ, Q4 + (size_t)b * sQ,
          lsum_part + (size_t)b * 64 * HW, S8, scl, 0, 0, 0);
      pv84<<<dim3(4, 32, 1), 256, 0, stream>>>(
          S8, V4 + (size_t)b * CH * (HW / 2),
          lsum_part + (size_t)b * 64 * HW, O8 + (size_t)b * HW * CH);
    }
  }

  projmx<<<dim3(4, TOKENS / 128), 256, 0, stream>>>(O8, Wp8, bp, x, out);
}